// Round 10
// baseline (222.716 us; speedup 1.0000x reference)
//
#include <hip/hip_runtime.h>
#include <hip/hip_bf16.h>

typedef __bf16 bf16x8 __attribute__((ext_vector_type(8)));
typedef __bf16 bf16x4 __attribute__((ext_vector_type(4)));
typedef __bf16 bf16x2 __attribute__((ext_vector_type(2)));
typedef float fx4 __attribute__((ext_vector_type(4)));
typedef float fx16 __attribute__((ext_vector_type(16)));

#define AS1 __attribute__((address_space(1)))
#define AS3 __attribute__((address_space(3)))

// ---------------------------------------------------------------- prep: cast x -> bf16  +  all 4 weight transposes
__global__ __launch_bounds__(256) void prep(const float4* __restrict__ X, __bf16* __restrict__ Xb,
                                            const float* __restrict__ wq, const float* __restrict__ wk,
                                            const float* __restrict__ wv, const float* __restrict__ wo,
                                            __bf16* __restrict__ WqkvT, __bf16* __restrict__ WoT) {
    const int bx = blockIdx.x;
    if (bx < 4096) {
        const int i = bx * 256 + threadIdx.x;
        const float4 v = X[i];
        bf16x4 o = { (__bf16)v.x, (__bf16)v.y, (__bf16)v.z, (__bf16)v.w };
        *(bf16x4*)(Xb + (size_t)i * 4) = o;
        return;
    }
    constexpr int K = 2048;
    __shared__ float t[64][65];
    const int tt = bx - 4096;
    const float* W; __bf16* Wt; int N, loc;
    if (tt < 1024)      { W = wq; Wt = WqkvT;                       N = 2048; loc = tt; }
    else if (tt < 1280) { W = wk; Wt = WqkvT + (size_t)2048 * 2048; N = 512;  loc = tt - 1024; }
    else if (tt < 1536) { W = wv; Wt = WqkvT + (size_t)2560 * 2048; N = 512;  loc = tt - 1280; }
    else                { W = wo; Wt = WoT;                         N = 2048; loc = tt - 1536; }
    const int k0 = (loc & 31) * 64, n0 = (loc >> 5) * 64;
    const int tx = threadIdx.x & 15, ty = threadIdx.x >> 4;
#pragma unroll
    for (int p = 0; p < 4; ++p) {
        const float4 v = *(const float4*)&W[(size_t)(k0 + p * 16 + ty) * N + n0 + tx * 4];
        t[p * 16 + ty][tx * 4 + 0] = v.x;
        t[p * 16 + ty][tx * 4 + 1] = v.y;
        t[p * 16 + ty][tx * 4 + 2] = v.z;
        t[p * 16 + ty][tx * 4 + 3] = v.w;
    }
    __syncthreads();
#pragma unroll
    for (int p = 0; p < 4; ++p) {
        const int nn = p * 16 + ty;
        bf16x4 o = { (__bf16)t[tx * 4 + 0][nn], (__bf16)t[tx * 4 + 1][nn],
                     (__bf16)t[tx * 4 + 2][nn], (__bf16)t[tx * 4 + 3][nn] };
        *(bf16x4*)&Wt[(size_t)(n0 + nn) * K + k0 + tx * 4] = o;
    }
}

// ================================================= shared GEMM body: BM=128 BN=128 BK=32,
// 4 waves (64x64 wave-tile), 3-buffer depth-2 counted-vmcnt ring (48KB -> 3 blocks/CU),
// static buffer indices, XOR-swizzled LDS. 16 MFMA : 8 ds_read_b128 per K-step.
#define GL(p, d) __builtin_amdgcn_global_load_lds((const AS1 void*)(p), (AS3 void*)(d), 16, 0, 0)
#define WBAR(N)  asm volatile("s_waitcnt vmcnt(" #N ") lgkmcnt(0)" ::: "memory");             \
                 __builtin_amdgcn_s_barrier();                                                \
                 __builtin_amdgcn_sched_barrier(0)

#define GEMM_SETUP(Aptr, Btptr)                                                              \
    constexpr int K = 2048;                                                                  \
    __shared__ __align__(16) __bf16 sm[3][8192];    /* 48 KB */                              \
    const int tid = threadIdx.x;                                                             \
    const int wave = tid >> 6, lane = tid & 63;                                              \
    const int quad = lane >> 4, l16 = lane & 15;                                             \
    const int wm = (wave >> 1) * 64, wn = (wave & 1) * 64;                                   \
    fx4 acc[4][4] = {};                                                                      \
    const int r4 = lane >> 2;                                                                \
    const int c8s = ((lane & 3) ^ ((r4 >> 1) & 3)) * 8;                                      \
    const __bf16* csrc[4]; int cdst[4];                                                      \
    _Pragma("unroll")                                                                        \
    for (int it = 0; it < 4; ++it) {                                                         \
        const int idx = wave * 4 + it;                                                       \
        if (idx < 8) { csrc[it] = (Aptr) + (size_t)(m0 + idx * 16 + r4) * K + c8s;           \
                       cdst[it] = idx * 512 + lane * 8; }                                    \
        else         { csrc[it] = (Btptr) + (size_t)(n0 + (idx - 8) * 16 + r4) * K + c8s;    \
                       cdst[it] = 4096 + (idx - 8) * 512 + lane * 8; }                       \
    }                                                                                        \
    const int colr = (quad ^ ((l16 >> 1) & 3)) * 8;                                          \
    const int arow = (wm + l16) * 32 + colr;                                                 \
    const int brow = 4096 + (wn + l16) * 32 + colr;                                          \
    auto compute = [&](const __bf16* cb) {                                                   \
        bf16x8 af[4], bfr[4];                                                                \
        _Pragma("unroll") for (int i = 0; i < 4; ++i) af[i]  = *(const bf16x8*)&cb[arow + i * 512]; \
        _Pragma("unroll") for (int j = 0; j < 4; ++j) bfr[j] = *(const bf16x8*)&cb[brow + j * 512]; \
        __builtin_amdgcn_s_setprio(1);                                                       \
        _Pragma("unroll") for (int i = 0; i < 4; ++i)                                        \
            _Pragma("unroll") for (int j = 0; j < 4; ++j)                                    \
                acc[i][j] = __builtin_amdgcn_mfma_f32_16x16x32_bf16(af[i], bfr[j], acc[i][j], 0, 0, 0); \
        __builtin_amdgcn_s_setprio(0);                                                       \
    };                                                                                       \
    _Pragma("unroll")                                                                        \
    for (int pt = 0; pt < 2; ++pt)                                                           \
        _Pragma("unroll")                                                                    \
        for (int it = 0; it < 4; ++it)                                                       \
            GL(csrc[it] + pt * 32, &sm[pt][cdst[it]]);                                       \
    _Pragma("unroll 1")                                                                      \
    for (int tq = 0; tq < 20; ++tq) {                                                        \
        _Pragma("unroll")                                                                    \
        for (int u = 0; u < 3; ++u) {                                                        \
            const int t = tq * 3 + u;                                                        \
            WBAR(4);                                                                         \
            const int kofs = (t + 2) * 32;                                                   \
            _Pragma("unroll")                                                                \
            for (int it = 0; it < 4; ++it)                                                   \
                GL(csrc[it] + kofs, &sm[(u + 2) % 3][cdst[it]]);                             \
            compute(sm[u]);                                                                  \
        }                                                                                    \
    }                                                                                        \
    { WBAR(4); _Pragma("unroll") for (int it = 0; it < 4; ++it)                              \
          GL(csrc[it] + 62 * 32, &sm[2][cdst[it]]); compute(sm[0]); }  /* t=60 */            \
    { WBAR(4); _Pragma("unroll") for (int it = 0; it < 4; ++it)                              \
          GL(csrc[it] + 63 * 32, &sm[0][cdst[it]]); compute(sm[1]); }  /* t=61 */            \
    { WBAR(4); compute(sm[2]); }                                       /* t=62 */            \
    { WBAR(0); compute(sm[0]); }                                       /* t=63 */

// ------------------------------------------------- QKV GEMM with fused RoPE/split epilogue
__global__ __launch_bounds__(256, 3) void gemm_qkv(const __bf16* __restrict__ A, const __bf16* __restrict__ Bt,
                                                   __bf16* __restrict__ Qr, __bf16* __restrict__ Kr,
                                                   __bf16* __restrict__ Vt) {
    // XCD-chunked swizzle, nwg = 384 = 8*48
    const int bid = blockIdx.x;
    const int swz = (bid & 7) * 48 + (bid >> 3);
    const int m0 = (swz & 15) * 128, n0 = (swz >> 4) * 128;

    GEMM_SETUP(A, Bt)

    // epilogue: each wave's 64 cols (col64..col64+63) are exactly one head
    const int col64 = n0 + wn;
    if (col64 < 2560) {
        const bool isQ = col64 < 2048;
        const float scale = isQ ? 0.18033688011112042f : 1.0f;   // Q: 0.125*log2(e)
        __bf16* base = isQ ? (Qr + (size_t)(col64 >> 6) * 2048 * 64)
                           : (Kr + (size_t)((col64 - 2048) >> 6) * 2048 * 64);
#pragma unroll
        for (int jj = 0; jj < 2; ++jj) {
            const int dlo = jj * 16 + l16;
            const float inv = __builtin_amdgcn_exp2f(-(float)dlo * 0.41524101186092029f);
#pragma unroll
            for (int i = 0; i < 4; ++i)
#pragma unroll
                for (int r = 0; r < 4; ++r) {
                    const int s = m0 + wm + i * 16 + quad * 4 + r;
                    float sn, cs;
                    __sincosf((float)s * inv, &sn, &cs);
                    const float lo = acc[i][jj][r], hv = acc[i][jj + 2][r];
                    base[(size_t)s * 64 + dlo]      = (__bf16)((lo * cs - hv * sn) * scale);
                    base[(size_t)s * 64 + dlo + 32] = (__bf16)((hv * cs + lo * sn) * scale);
                }
        }
    } else {
        __bf16* vb = Vt + (size_t)((col64 - 2560) >> 6) * 64 * 2048;
#pragma unroll
        for (int i = 0; i < 4; ++i)
#pragma unroll
            for (int j = 0; j < 4; ++j) {
                const int d = j * 16 + l16;
                const int s0 = m0 + wm + i * 16 + quad * 4;
                bf16x4 p;
#pragma unroll
                for (int r = 0; r < 4; ++r) p[r] = (__bf16)acc[i][j][r];
                *(bf16x4*)&vb[(size_t)d * 2048 + s0] = p;
            }
    }
}

// ------------------------------------------------- out-projection GEMM, f32 C direct
__global__ __launch_bounds__(256, 3) void gemm_out(const __bf16* __restrict__ A, const __bf16* __restrict__ Bt,
                                                   float* __restrict__ C) {
    // XCD-chunked swizzle, nwg = 256 = 8*32
    const int bid = blockIdx.x;
    const int swz = (bid & 7) * 32 + (bid >> 3);
    const int m0 = (swz & 15) * 128, n0 = (swz >> 4) * 128;

    GEMM_SETUP(A, Bt)

#pragma unroll
    for (int i = 0; i < 4; ++i)
#pragma unroll
        for (int j = 0; j < 4; ++j) {
            const int row = m0 + wm + i * 16 + quad * 4;
            const int col = n0 + wn + j * 16 + l16;
#pragma unroll
            for (int r = 0; r < 4; ++r)
                C[(size_t)(row + r) * 2048 + col] = acc[i][j][r];
        }
}

// ------------------------------------------------- flash attention: r6 structure + (a) XCD-kvh
// block swizzle (each XCD owns one kvh's K/V -> L2-local), (b) T15 QK/PV software pipeline:
// per iter compute PV(it) [scores from last iter] in parallel with QK(it+1) [K staged this
// iter]; scores double-buffered scA/scB (static names). 2 barriers/iter (stage-visible before
// QK(next); reads-drained before next stage). Buffer discipline otherwise identical to r6.
__global__ __launch_bounds__(512, 4) void flash_attn(const __bf16* __restrict__ Qr, const __bf16* __restrict__ Kr,
                                                     const __bf16* __restrict__ Vt, __bf16* __restrict__ O) {
    constexpr int S = 2048;
    __shared__ __align__(16) __bf16 smem[2][4 * 64 * 72];   // 73728 B, 2 buffers
    // XCD-aware decode: 512 blocks, round-robin XCD = bid&7 -> XCD i serves kvh i only.
    const int bid = blockIdx.x;
    const int o = bid >> 3;
    const int kvh = bid & 7;
    const int h = kvh * 4 + (o & 3);
    const int qt = o >> 2;
    const int tid = threadIdx.x, wave = tid >> 6, lane = tid & 63;
    const int grp = wave >> 2, w4 = wave & 3;
    const int l32 = lane & 31, hi = lane >> 5;
    const int goff = grp * 2 * 4608;                        // group's K/V region inside a buffer

    const int qrow = qt * 128 + w4 * 32 + l32;
    const __bf16* qptr = Qr + ((size_t)h * S + qrow) * 64;
    bf16x8 qf[4];
#pragma unroll
    for (int kc = 0; kc < 4; ++kc) qf[kc] = *(const bf16x8*)(qptr + kc * 16 + hi * 8);

    const __bf16* Kbase = Kr + (size_t)kvh * S * 64;
    const __bf16* Vbase = Vt + (size_t)kvh * 64 * S;

    const int gtid = tid & 255;
    const int krow = gtid >> 3;                 // 0..31
    const int kcol = (gtid & 7) * 8;
    const int vslot = (kcol & 48) | ((kcol & 8) >> 1);   // permuted dest of keys [kcol, kcol+4)

    bf16x8 kreg0, kreg1, vreg0, vreg1;

#define LOADREGS(ITN) do {                                                            \
        const int ktn_ = (ITN) * 2 + grp;                                             \
        kreg0 = *(const bf16x8*)(Kbase + (size_t)(ktn_ * 64 + krow) * 64 + kcol);     \
        kreg1 = *(const bf16x8*)(Kbase + (size_t)(ktn_ * 64 + 32 + krow) * 64 + kcol);\
        vreg0 = *(const bf16x8*)(Vbase + (size_t)krow * S + ktn_ * 64 + kcol);        \
        vreg1 = *(const bf16x8*)(Vbase + (size_t)(32 + krow) * S + ktn_ * 64 + kcol); \
    } while (0)

#define STAGEB(BUF) do {                                                              \
        __bf16* nK = &smem[BUF][goff];                                                \
        __bf16* nV = nK + 4608;                                                       \
        *(bf16x8*)&nK[krow * 72 + kcol] = kreg0;                                      \
        *(bf16x8*)&nK[(32 + krow) * 72 + kcol] = kreg1;                               \
        bf16x4 v0lo = { vreg0[0], vreg0[1], vreg0[2], vreg0[3] };                     \
        bf16x4 v0hi = { vreg0[4], vreg0[5], vreg0[6], vreg0[7] };                     \
        bf16x4 v1lo = { vreg1[0], vreg1[1], vreg1[2], vreg1[3] };                     \
        bf16x4 v1hi = { vreg1[4], vreg1[5], vreg1[6], vreg1[7] };                     \
        *(bf16x4*)&nV[krow * 72 + vslot]            = v0lo;                           \
        *(bf16x4*)&nV[krow * 72 + vslot + 8]        = v0hi;                           \
        *(bf16x4*)&nV[(32 + krow) * 72 + vslot]     = v1lo;                           \
        *(bf16x4*)&nV[(32 + krow) * 72 + vslot + 8] = v1hi;                           \
    } while (0)

#define QKST(D0, D1, LKG) do {                                                        \
        _Pragma("unroll") for (int i_ = 0; i_ < 16; ++i_) { (D0)[i_] = 0.f; (D1)[i_] = 0.f; } \
        __builtin_amdgcn_s_setprio(1);                                                \
        _Pragma("unroll")                                                             \
        for (int kc = 0; kc < 4; ++kc) {                                              \
            const bf16x8 a0 = *(const bf16x8*)&(LKG)[l32 * 72 + kc * 16 + hi * 8];    \
            const bf16x8 a1 = *(const bf16x8*)&(LKG)[(32 + l32) * 72 + kc * 16 + hi * 8]; \
            (D0) = __builtin_amdgcn_mfma_f32_32x32x16_bf16(a0, qf[kc], (D0), 0, 0, 0);\
            (D1) = __builtin_amdgcn_mfma_f32_32x32x16_bf16(a1, qf[kc], (D1), 0, 0, 0);\
        }                                                                             \
        __builtin_amdgcn_s_setprio(0);                                                \
    } while (0)

#define PVPH(LVG, S0, S1) do {                                                        \
        _Pragma("unroll")                                                             \
        for (int h2 = 0; h2 < 2; ++h2) {                                              \
            _Pragma("unroll")                                                         \
            for (int c = 0; c < 2; ++c) {                                             \
                bf16x8 pb; float ps[8];                                               \
                _Pragma("unroll")                                                     \
                for (int j = 0; j < 8; ++j) {                                         \
                    const float sv = h2 ? (S1)[c * 8 + j] : (S0)[c * 8 + j];          \
                    ps[j] = __builtin_amdgcn_exp2f(sv);                               \
                    pb[j] = (__bf16)ps[j];                                            \
                }                                                                     \
                l_acc += ((ps[0] + ps[1]) + (ps[2] + ps[3]))                          \
                       + ((ps[4] + ps[5]) + (ps[6] + ps[7]));                         \
                const int kcv = h2 * 2 + c;                                           \
                const bf16x8 va0 = *(const bf16x8*)&(LVG)[l32 * 72 + kcv * 16 + hi * 8]; \
                const bf16x8 va1 = *(const bf16x8*)&(LVG)[(32 + l32) * 72 + kcv * 16 + hi * 8]; \
                __builtin_amdgcn_s_setprio(1);                                        \
                ov0 = __builtin_amdgcn_mfma_f32_32x32x16_bf16(va0, pb, ov0, 0, 0, 0); \
                ov1 = __builtin_amdgcn_mfma_f32_32x32x16_bf16(va1, pb, ov1, 0, 0, 0); \
                __builtin_amdgcn_s_setprio(0);                                        \
            }                                                                         \
        }                                                                             \
    } while (0)

#define LGKMBAR() do {                                                                \
        asm volatile("s_waitcnt lgkmcnt(0)" ::: "memory");                            \
        __builtin_amdgcn_s_barrier();                                                 \
        __builtin_amdgcn_sched_barrier(0);                                            \
    } while (0)

// one pipelined iteration: stage tile IT+1 into BUFW, prefetch IT+2, then PV(IT) || QK(IT+1)
#define FITER(IT, BUFR, BUFW, SCP0, SCP1, SCQ0, SCQ1) do {                            \
        STAGEB(BUFW);                                                                 \
        LOADREGS(((IT) + 2 < 16) ? (IT) + 2 : 15);                                    \
        LGKMBAR();                                                                    \
        PVPH(&smem[BUFR][goff] + 4608, SCP0, SCP1);                                   \
        QKST(SCQ0, SCQ1, &smem[BUFW][goff]);                                          \
        LGKMBAR();                                                                    \
    } while (0)

    fx16 ov0, ov1;
#pragma unroll
    for (int i = 0; i < 16; ++i) { ov0[i] = 0.f; ov1[i] = 0.f; }
    float l_acc = 0.f;

    // prologue: stage tile 0 into buf 0, prefetch tile 1, then QK(0) -> scA
    LOADREGS(0);
    STAGEB(0);
    LOADREGS(1);
    LGKMBAR();

    fx16 scA0, scA1, scB0, scB1;
    QKST(scA0, scA1, &smem[0][goff]);
    LGKMBAR();

#pragma unroll 1
    for (int t = 0; t < 7; ++t) {
        FITER(2 * t,     0, 1, scA0, scA1, scB0, scB1);   // even it: PV(it,scA), QK(it+1)->scB
        FITER(2 * t + 1, 1, 0, scB0, scB1, scA0, scA1);   // odd  it: PV(it,scB), QK(it+1)->scA
    }
    FITER(14, 0, 1, scA0, scA1, scB0, scB1);              // it=14: PV(14,scA), QK(15)->scB
    PVPH(&smem[1][goff] + 4608, scB0, scB1);              // it=15: PV(15,scB)

    // per-wave l over this group's keys (partner lane^32 holds complement)
    const float l_pair = l_acc + __shfl_xor(l_acc, 32, 64);

    // cross-group combine, overlaid on smem[0]
    fx4* lO = (fx4*)&smem[0][0];                 // [8 chunks][4 w4][64 lanes]
    float* lL = (float*)(&smem[0][0] + 16384);   // byte 32768
    __syncthreads();                             // drain last PV reads before overlay writes
    if (grp == 1) {
#pragma unroll
        for (int ic = 0; ic < 4; ++ic) {
            fx4 c0, c1;
#pragma unroll
            for (int r = 0; r < 4; ++r) { c0[r] = ov0[ic * 4 + r]; c1[r] = ov1[ic * 4 + r]; }
            lO[(ic * 4 + w4) * 64 + lane] = c0;
            lO[((ic + 4) * 4 + w4) * 64 + lane] = c1;
        }
        if (hi == 0) lL[w4 * 32 + l32] = l_pair;
    }
    __syncthreads();
    if (grp == 0) {
#pragma unroll
        for (int ic = 0; ic < 4; ++ic) {
            const fx4 c0 = lO[(ic * 4 + w4) * 64 + lane];
            const fx4 c1 = lO[((ic + 4) * 4 + w4) * 64 + lane];
#pragma unroll
            for (int r = 0; r < 4; ++r) { ov0[ic * 4 + r] += c0[r]; ov1[ic * 4 + r] += c1[r]; }
        }
        const float inv_l = 1.0f / (l_pair + lL[w4 * 32 + l32]);
#pragma unroll
        for (int dt = 0; dt < 2; ++dt)
#pragma unroll
            for (int rg2 = 0; rg2 < 4; ++rg2) {
                bf16x4 o4;
#pragma unroll
                for (int r = 0; r < 4; ++r)
                    o4[r] = (__bf16)((dt ? ov1[rg2 * 4 + r] : ov0[rg2 * 4 + r]) * inv_l);
                const int col = h * 64 + dt * 32 + rg2 * 8 + hi * 4;
                *(bf16x4*)(O + (size_t)qrow * 2048 + col) = o4;
            }
    }
#undef LOADREGS
#undef STAGEB
#undef QKST
#undef PVPH
#undef LGKMBAR
#undef FITER
}

// ----------------------------------------------------------------------------
extern "C" void kernel_launch(void* const* d_in, const int* in_sizes, int n_in,
                              void* d_out, int out_size, void* d_ws, size_t ws_size,
                              hipStream_t stream) {
    const float* x  = (const float*)d_in[0];
    const float* wq = (const float*)d_in[1];
    const float* wk = (const float*)d_in[2];
    const float* wv = (const float*)d_in[3];
    const float* wo = (const float*)d_in[4];
    float* out = (float*)d_out;
    char* ws = (char*)d_ws;

    __bf16* Xb    = (__bf16*)ws;                        // [0, 8M)
    __bf16* WqkvT = (__bf16*)(ws + ((size_t)8 << 20));  // [8M, 20M)  3072 x 2048
    __bf16* WoT   = (__bf16*)(ws + ((size_t)20 << 20)); // [20M, 28M) 2048 x 2048
    __bf16* Qr    = (__bf16*)(ws + ((size_t)28 << 20)); // [28M, 36M) 32 x 2048 x 64
    __bf16* Kr    = (__bf16*)(ws + ((size_t)36 << 20)); // [36M, 38M)  8 x 2048 x 64
    __bf16* Vt    = (__bf16*)(ws + ((size_t)38 << 20)); // [38M, 40M)  8 x 64 x 2048
    __bf16* Ob    = (__bf16*)(ws + ((size_t)40 << 20)); // [40M, 48M) 2048 x 2048

    prep<<<4096 + 2560, 256, 0, stream>>>((const float4*)x, Xb, wq, wk, wv, wo, WqkvT, WoT);
    gemm_qkv<<<384, 256, 0, stream>>>(Xb, WqkvT, Qr, Kr, Vt);
    flash_attn<<<512, 512, 0, stream>>>(Qr, Kr, Vt, Ob);
    gemm_out<<<256, 256, 0, stream>>>(Ob, WoT, out);
}

// Round 11
// 198.071 us; speedup vs baseline: 1.1244x; 1.1244x over previous
//
#include <hip/hip_runtime.h>
#include <hip/hip_bf16.h>

typedef __bf16 bf16x8 __attribute__((ext_vector_type(8)));
typedef __bf16 bf16x4 __attribute__((ext_vector_type(4)));
typedef __bf16 bf16x2 __attribute__((ext_vector_type(2)));
typedef float fx4 __attribute__((ext_vector_type(4)));
typedef float fx16 __attribute__((ext_vector_type(16)));

#define AS1 __attribute__((address_space(1)))
#define AS3 __attribute__((address_space(3)))

// ---------------------------------------------------------------- prep: cast x -> bf16  +  all 4 weight transposes
__global__ __launch_bounds__(256) void prep(const float4* __restrict__ X, __bf16* __restrict__ Xb,
                                            const float* __restrict__ wq, const float* __restrict__ wk,
                                            const float* __restrict__ wv, const float* __restrict__ wo,
                                            __bf16* __restrict__ WqkvT, __bf16* __restrict__ WoT) {
    const int bx = blockIdx.x;
    if (bx < 4096) {
        const int i = bx * 256 + threadIdx.x;
        const float4 v = X[i];
        bf16x4 o = { (__bf16)v.x, (__bf16)v.y, (__bf16)v.z, (__bf16)v.w };
        *(bf16x4*)(Xb + (size_t)i * 4) = o;
        return;
    }
    constexpr int K = 2048;
    __shared__ float t[64][65];
    const int tt = bx - 4096;
    const float* W; __bf16* Wt; int N, loc;
    if (tt < 1024)      { W = wq; Wt = WqkvT;                       N = 2048; loc = tt; }
    else if (tt < 1280) { W = wk; Wt = WqkvT + (size_t)2048 * 2048; N = 512;  loc = tt - 1024; }
    else if (tt < 1536) { W = wv; Wt = WqkvT + (size_t)2560 * 2048; N = 512;  loc = tt - 1280; }
    else                { W = wo; Wt = WoT;                         N = 2048; loc = tt - 1536; }
    const int k0 = (loc & 31) * 64, n0 = (loc >> 5) * 64;
    const int tx = threadIdx.x & 15, ty = threadIdx.x >> 4;
#pragma unroll
    for (int p = 0; p < 4; ++p) {
        const float4 v = *(const float4*)&W[(size_t)(k0 + p * 16 + ty) * N + n0 + tx * 4];
        t[p * 16 + ty][tx * 4 + 0] = v.x;
        t[p * 16 + ty][tx * 4 + 1] = v.y;
        t[p * 16 + ty][tx * 4 + 2] = v.z;
        t[p * 16 + ty][tx * 4 + 3] = v.w;
    }
    __syncthreads();
#pragma unroll
    for (int p = 0; p < 4; ++p) {
        const int nn = p * 16 + ty;
        bf16x4 o = { (__bf16)t[tx * 4 + 0][nn], (__bf16)t[tx * 4 + 1][nn],
                     (__bf16)t[tx * 4 + 2][nn], (__bf16)t[tx * 4 + 3][nn] };
        *(bf16x4*)&Wt[(size_t)(n0 + nn) * K + k0 + tx * 4] = o;
    }
}

// ================================================= shared GEMM body: BM=128 BN=128 BK=32,
// 4 waves (64x64 wave-tile), 3-buffer depth-2 counted-vmcnt ring (48KB -> 3 blocks/CU),
// static buffer indices, XOR-swizzled LDS. 16 MFMA : 8 ds_read_b128 per K-step.
#define GL(p, d) __builtin_amdgcn_global_load_lds((const AS1 void*)(p), (AS3 void*)(d), 16, 0, 0)
#define WBAR(N)  asm volatile("s_waitcnt vmcnt(" #N ") lgkmcnt(0)" ::: "memory");             \
                 __builtin_amdgcn_s_barrier();                                                \
                 __builtin_amdgcn_sched_barrier(0)

#define GEMM_SETUP(Aptr, Btptr)                                                              \
    constexpr int K = 2048;                                                                  \
    __shared__ __align__(16) __bf16 sm[3][8192];    /* 48 KB */                              \
    const int tid = threadIdx.x;                                                             \
    const int wave = tid >> 6, lane = tid & 63;                                              \
    const int quad = lane >> 4, l16 = lane & 15;                                             \
    const int wm = (wave >> 1) * 64, wn = (wave & 1) * 64;                                   \
    fx4 acc[4][4] = {};                                                                      \
    const int r4 = lane >> 2;                                                                \
    const int c8s = ((lane & 3) ^ ((r4 >> 1) & 3)) * 8;                                      \
    const __bf16* csrc[4]; int cdst[4];                                                      \
    _Pragma("unroll")                                                                        \
    for (int it = 0; it < 4; ++it) {                                                         \
        const int idx = wave * 4 + it;                                                       \
        if (idx < 8) { csrc[it] = (Aptr) + (size_t)(m0 + idx * 16 + r4) * K + c8s;           \
                       cdst[it] = idx * 512 + lane * 8; }                                    \
        else         { csrc[it] = (Btptr) + (size_t)(n0 + (idx - 8) * 16 + r4) * K + c8s;    \
                       cdst[it] = 4096 + (idx - 8) * 512 + lane * 8; }                       \
    }                                                                                        \
    const int colr = (quad ^ ((l16 >> 1) & 3)) * 8;                                          \
    const int arow = (wm + l16) * 32 + colr;                                                 \
    const int brow = 4096 + (wn + l16) * 32 + colr;                                          \
    auto compute = [&](const __bf16* cb) {                                                   \
        bf16x8 af[4], bfr[4];                                                                \
        _Pragma("unroll") for (int i = 0; i < 4; ++i) af[i]  = *(const bf16x8*)&cb[arow + i * 512]; \
        _Pragma("unroll") for (int j = 0; j < 4; ++j) bfr[j] = *(const bf16x8*)&cb[brow + j * 512]; \
        __builtin_amdgcn_s_setprio(1);                                                       \
        _Pragma("unroll") for (int i = 0; i < 4; ++i)                                        \
            _Pragma("unroll") for (int j = 0; j < 4; ++j)                                    \
                acc[i][j] = __builtin_amdgcn_mfma_f32_16x16x32_bf16(af[i], bfr[j], acc[i][j], 0, 0, 0); \
        __builtin_amdgcn_s_setprio(0);                                                       \
    };                                                                                       \
    _Pragma("unroll")                                                                        \
    for (int pt = 0; pt < 2; ++pt)                                                           \
        _Pragma("unroll")                                                                    \
        for (int it = 0; it < 4; ++it)                                                       \
            GL(csrc[it] + pt * 32, &sm[pt][cdst[it]]);                                       \
    _Pragma("unroll 1")                                                                      \
    for (int tq = 0; tq < 20; ++tq) {                                                        \
        _Pragma("unroll")                                                                    \
        for (int u = 0; u < 3; ++u) {                                                        \
            const int t = tq * 3 + u;                                                        \
            WBAR(4);                                                                         \
            const int kofs = (t + 2) * 32;                                                   \
            _Pragma("unroll")                                                                \
            for (int it = 0; it < 4; ++it)                                                   \
                GL(csrc[it] + kofs, &sm[(u + 2) % 3][cdst[it]]);                             \
            compute(sm[u]);                                                                  \
        }                                                                                    \
    }                                                                                        \
    { WBAR(4); _Pragma("unroll") for (int it = 0; it < 4; ++it)                              \
          GL(csrc[it] + 62 * 32, &sm[2][cdst[it]]); compute(sm[0]); }  /* t=60 */            \
    { WBAR(4); _Pragma("unroll") for (int it = 0; it < 4; ++it)                              \
          GL(csrc[it] + 63 * 32, &sm[0][cdst[it]]); compute(sm[1]); }  /* t=61 */            \
    { WBAR(4); compute(sm[2]); }                                       /* t=62 */            \
    { WBAR(0); compute(sm[0]); }                                       /* t=63 */

// ------------------------------------------------- QKV GEMM with fused RoPE/split epilogue
__global__ __launch_bounds__(256, 3) void gemm_qkv(const __bf16* __restrict__ A, const __bf16* __restrict__ Bt,
                                                   __bf16* __restrict__ Qr, __bf16* __restrict__ Kr,
                                                   __bf16* __restrict__ Vt) {
    // XCD-chunked swizzle, nwg = 384 = 8*48
    const int bid = blockIdx.x;
    const int swz = (bid & 7) * 48 + (bid >> 3);
    const int m0 = (swz & 15) * 128, n0 = (swz >> 4) * 128;

    GEMM_SETUP(A, Bt)

    // epilogue: each wave's 64 cols (col64..col64+63) are exactly one head
    const int col64 = n0 + wn;
    if (col64 < 2560) {
        const bool isQ = col64 < 2048;
        const float scale = isQ ? 0.18033688011112042f : 1.0f;   // Q: 0.125*log2(e)
        __bf16* base = isQ ? (Qr + (size_t)(col64 >> 6) * 2048 * 64)
                           : (Kr + (size_t)((col64 - 2048) >> 6) * 2048 * 64);
#pragma unroll
        for (int jj = 0; jj < 2; ++jj) {
            const int dlo = jj * 16 + l16;
            const float inv = __builtin_amdgcn_exp2f(-(float)dlo * 0.41524101186092029f);
#pragma unroll
            for (int i = 0; i < 4; ++i)
#pragma unroll
                for (int r = 0; r < 4; ++r) {
                    const int s = m0 + wm + i * 16 + quad * 4 + r;
                    float sn, cs;
                    __sincosf((float)s * inv, &sn, &cs);
                    const float lo = acc[i][jj][r], hv = acc[i][jj + 2][r];
                    base[(size_t)s * 64 + dlo]      = (__bf16)((lo * cs - hv * sn) * scale);
                    base[(size_t)s * 64 + dlo + 32] = (__bf16)((hv * cs + lo * sn) * scale);
                }
        }
    } else {
        __bf16* vb = Vt + (size_t)((col64 - 2560) >> 6) * 64 * 2048;
#pragma unroll
        for (int i = 0; i < 4; ++i)
#pragma unroll
            for (int j = 0; j < 4; ++j) {
                const int d = j * 16 + l16;
                const int s0 = m0 + wm + i * 16 + quad * 4;
                bf16x4 p;
#pragma unroll
                for (int r = 0; r < 4; ++r) p[r] = (__bf16)acc[i][j][r];
                *(bf16x4*)&vb[(size_t)d * 2048 + s0] = p;
            }
    }
}

// ------------------------------------------------- out-projection GEMM, f32 C direct
__global__ __launch_bounds__(256, 3) void gemm_out(const __bf16* __restrict__ A, const __bf16* __restrict__ Bt,
                                                   float* __restrict__ C) {
    // XCD-chunked swizzle, nwg = 256 = 8*32
    const int bid = blockIdx.x;
    const int swz = (bid & 7) * 32 + (bid >> 3);
    const int m0 = (swz & 15) * 128, n0 = (swz >> 4) * 128;

    GEMM_SETUP(A, Bt)

#pragma unroll
    for (int i = 0; i < 4; ++i)
#pragma unroll
        for (int j = 0; j < 4; ++j) {
            const int row = m0 + wm + i * 16 + quad * 4;
            const int col = n0 + wn + j * 16 + l16;
#pragma unroll
            for (int r = 0; r < 4; ++r)
                C[(size_t)(row + r) * 2048 + col] = acc[i][j][r];
        }
}

// ------------------------------------------------- flash attention: r6-proven structure + XCD-kvh
// block decode ONLY (1-D grid 512; XCD i = bid&7 serves kvh i -> per-XCD K/V working set 0.5MB,
// L2-resident). K AND V staged in LDS, permuted-V, raw lgkm barriers, l_acc octet tree-sums.
// VGPR 64, no spill (r4/r10 lesson: this structure has zero VGPR headroom).
__global__ __launch_bounds__(512, 4) void flash_attn(const __bf16* __restrict__ Qr, const __bf16* __restrict__ Kr,
                                                     const __bf16* __restrict__ Vt, __bf16* __restrict__ O) {
    constexpr int S = 2048;
    __shared__ __align__(16) __bf16 smem[2][4 * 64 * 72];   // 73728 B, 2 buffers
    // XCD-aware decode: 512 blocks, XCD = bid&7 -> XCD i serves kvh i only.
    const int bid = blockIdx.x;
    const int o = bid >> 3;
    const int kvh = bid & 7;
    const int h = kvh * 4 + (o & 3);
    const int qt = o >> 2;
    const int tid = threadIdx.x, wave = tid >> 6, lane = tid & 63;
    const int grp = wave >> 2, w4 = wave & 3;
    const int l32 = lane & 31, hi = lane >> 5;
    const int goff = grp * 2 * 4608;                        // group's K/V region inside a buffer

    const int qrow = qt * 128 + w4 * 32 + l32;
    const __bf16* qptr = Qr + ((size_t)h * S + qrow) * 64;
    bf16x8 qf[4];
#pragma unroll
    for (int kc = 0; kc < 4; ++kc) qf[kc] = *(const bf16x8*)(qptr + kc * 16 + hi * 8);

    const __bf16* Kbase = Kr + (size_t)kvh * S * 64;
    const __bf16* Vbase = Vt + (size_t)kvh * 64 * S;

    const int gtid = tid & 255;
    const int krow = gtid >> 3;                 // 0..31
    const int kcol = (gtid & 7) * 8;
    const int vslot = (kcol & 48) | ((kcol & 8) >> 1);   // permuted dest of keys [kcol, kcol+4)

    // prefetch tile 0 of this group (kt = grp)
    bf16x8 kreg0 = *(const bf16x8*)(Kbase + (size_t)(grp * 64 + krow) * 64 + kcol);
    bf16x8 kreg1 = *(const bf16x8*)(Kbase + (size_t)(grp * 64 + 32 + krow) * 64 + kcol);
    bf16x8 vreg0 = *(const bf16x8*)(Vbase + (size_t)krow * S + grp * 64 + kcol);
    bf16x8 vreg1 = *(const bf16x8*)(Vbase + (size_t)(32 + krow) * S + grp * 64 + kcol);

    fx16 ov0, ov1;
#pragma unroll
    for (int i = 0; i < 16; ++i) { ov0[i] = 0.f; ov1[i] = 0.f; }
    float l_acc = 0.f;

    // stage tile 0 into buf 0, then prefetch tile 1 (kt = 2 + grp)
    {
        __bf16* nK = &smem[0][goff];
        __bf16* nV = nK + 4608;
        *(bf16x8*)&nK[krow * 72 + kcol] = kreg0;
        *(bf16x8*)&nK[(32 + krow) * 72 + kcol] = kreg1;
        bf16x4 v0lo = { vreg0[0], vreg0[1], vreg0[2], vreg0[3] };
        bf16x4 v0hi = { vreg0[4], vreg0[5], vreg0[6], vreg0[7] };
        bf16x4 v1lo = { vreg1[0], vreg1[1], vreg1[2], vreg1[3] };
        bf16x4 v1hi = { vreg1[4], vreg1[5], vreg1[6], vreg1[7] };
        *(bf16x4*)&nV[krow * 72 + vslot]            = v0lo;
        *(bf16x4*)&nV[krow * 72 + vslot + 8]        = v0hi;
        *(bf16x4*)&nV[(32 + krow) * 72 + vslot]     = v1lo;
        *(bf16x4*)&nV[(32 + krow) * 72 + vslot + 8] = v1hi;
        const int kt1 = 2 + grp;
        kreg0 = *(const bf16x8*)(Kbase + (size_t)(kt1 * 64 + krow) * 64 + kcol);
        kreg1 = *(const bf16x8*)(Kbase + (size_t)(kt1 * 64 + 32 + krow) * 64 + kcol);
        vreg0 = *(const bf16x8*)(Vbase + (size_t)krow * S + kt1 * 64 + kcol);
        vreg1 = *(const bf16x8*)(Vbase + (size_t)(32 + krow) * S + kt1 * 64 + kcol);
    }
    asm volatile("s_waitcnt lgkmcnt(0)" ::: "memory");
    __builtin_amdgcn_s_barrier();
    __builtin_amdgcn_sched_barrier(0);

    for (int it = 0; it < 16; ++it) {
        __bf16* lKg = &smem[it & 1][goff];
        __bf16* lVg = lKg + 4608;

        // stage tile it+1 into the other buffer; prefetch tile it+2
        if (it + 1 < 16) {
            __bf16* nK = &smem[(it + 1) & 1][goff];
            __bf16* nV = nK + 4608;
            *(bf16x8*)&nK[krow * 72 + kcol] = kreg0;
            *(bf16x8*)&nK[(32 + krow) * 72 + kcol] = kreg1;
            bf16x4 v0lo = { vreg0[0], vreg0[1], vreg0[2], vreg0[3] };
            bf16x4 v0hi = { vreg0[4], vreg0[5], vreg0[6], vreg0[7] };
            bf16x4 v1lo = { vreg1[0], vreg1[1], vreg1[2], vreg1[3] };
            bf16x4 v1hi = { vreg1[4], vreg1[5], vreg1[6], vreg1[7] };
            *(bf16x4*)&nV[krow * 72 + vslot]            = v0lo;
            *(bf16x4*)&nV[krow * 72 + vslot + 8]        = v0hi;
            *(bf16x4*)&nV[(32 + krow) * 72 + vslot]     = v1lo;
            *(bf16x4*)&nV[(32 + krow) * 72 + vslot + 8] = v1hi;
            const int it2 = (it + 2 < 16) ? it + 2 : 15;   // clamped (redundant reload ok)
            const int ktn = it2 * 2 + grp;
            kreg0 = *(const bf16x8*)(Kbase + (size_t)(ktn * 64 + krow) * 64 + kcol);
            kreg1 = *(const bf16x8*)(Kbase + (size_t)(ktn * 64 + 32 + krow) * 64 + kcol);
            vreg0 = *(const bf16x8*)(Vbase + (size_t)krow * S + ktn * 64 + kcol);
            vreg1 = *(const bf16x8*)(Vbase + (size_t)(32 + krow) * S + ktn * 64 + kcol);
        }

        // S^T = K . Q^T  (k-chunks of 16 d)
        fx16 sc0, sc1;
#pragma unroll
        for (int i = 0; i < 16; ++i) { sc0[i] = 0.f; sc1[i] = 0.f; }
        __builtin_amdgcn_s_setprio(1);
#pragma unroll
        for (int kc = 0; kc < 4; ++kc) {
            const bf16x8 a0 = *(const bf16x8*)&lKg[l32 * 72 + kc * 16 + hi * 8];
            const bf16x8 a1 = *(const bf16x8*)&lKg[(32 + l32) * 72 + kc * 16 + hi * 8];
            sc0 = __builtin_amdgcn_mfma_f32_32x32x16_bf16(a0, qf[kc], sc0, 0, 0, 0);
            sc1 = __builtin_amdgcn_mfma_f32_32x32x16_bf16(a1, qf[kc], sc1, 0, 0, 0);
        }
        __builtin_amdgcn_s_setprio(0);

        // fixed-max softmax (p = exp2(s), Q pre-scaled) fused straight into PV;
        // l summed per-octet tree (depth 4)
#pragma unroll
        for (int h2 = 0; h2 < 2; ++h2) {
#pragma unroll
            for (int c = 0; c < 2; ++c) {
                bf16x8 pb; float ps[8];
#pragma unroll
                for (int j = 0; j < 8; ++j) {
                    const float sv = h2 ? sc1[c * 8 + j] : sc0[c * 8 + j];
                    ps[j] = __builtin_amdgcn_exp2f(sv);
                    pb[j] = (__bf16)ps[j];
                }
                l_acc += ((ps[0] + ps[1]) + (ps[2] + ps[3]))
                       + ((ps[4] + ps[5]) + (ps[6] + ps[7]));
                const int kcv = h2 * 2 + c;
                const bf16x8 va0 = *(const bf16x8*)&lVg[l32 * 72 + kcv * 16 + hi * 8];
                const bf16x8 va1 = *(const bf16x8*)&lVg[(32 + l32) * 72 + kcv * 16 + hi * 8];
                __builtin_amdgcn_s_setprio(1);
                ov0 = __builtin_amdgcn_mfma_f32_32x32x16_bf16(va0, pb, ov0, 0, 0, 0);
                ov1 = __builtin_amdgcn_mfma_f32_32x32x16_bf16(va1, pb, ov1, 0, 0, 0);
                __builtin_amdgcn_s_setprio(0);
            }
        }
        asm volatile("s_waitcnt lgkmcnt(0)" ::: "memory");
        __builtin_amdgcn_s_barrier();
        __builtin_amdgcn_sched_barrier(0);
    }

    // per-wave l over this group's keys (partner lane^32 holds complement)
    const float l_pair = l_acc + __shfl_xor(l_acc, 32, 64);

    // cross-group combine, overlaid on smem[0]
    fx4* lO = (fx4*)&smem[0][0];                 // [8 chunks][4 w4][64 lanes]
    float* lL = (float*)(&smem[0][0] + 16384);   // byte 32768
    if (grp == 1) {
#pragma unroll
        for (int ic = 0; ic < 4; ++ic) {
            fx4 c0, c1;
#pragma unroll
            for (int r = 0; r < 4; ++r) { c0[r] = ov0[ic * 4 + r]; c1[r] = ov1[ic * 4 + r]; }
            lO[(ic * 4 + w4) * 64 + lane] = c0;
            lO[((ic + 4) * 4 + w4) * 64 + lane] = c1;
        }
        if (hi == 0) lL[w4 * 32 + l32] = l_pair;
    }
    __syncthreads();
    if (grp == 0) {
#pragma unroll
        for (int ic = 0; ic < 4; ++ic) {
            const fx4 c0 = lO[(ic * 4 + w4) * 64 + lane];
            const fx4 c1 = lO[((ic + 4) * 4 + w4) * 64 + lane];
#pragma unroll
            for (int r = 0; r < 4; ++r) { ov0[ic * 4 + r] += c0[r]; ov1[ic * 4 + r] += c1[r]; }
        }
        const float inv_l = 1.0f / (l_pair + lL[w4 * 32 + l32]);
#pragma unroll
        for (int dt = 0; dt < 2; ++dt)
#pragma unroll
            for (int rg2 = 0; rg2 < 4; ++rg2) {
                bf16x4 o4;
#pragma unroll
                for (int r = 0; r < 4; ++r)
                    o4[r] = (__bf16)((dt ? ov1[rg2 * 4 + r] : ov0[rg2 * 4 + r]) * inv_l);
                const int col = h * 64 + dt * 32 + rg2 * 8 + hi * 4;
                *(bf16x4*)(O + (size_t)qrow * 2048 + col) = o4;
            }
    }
}

// ----------------------------------------------------------------------------
extern "C" void kernel_launch(void* const* d_in, const int* in_sizes, int n_in,
                              void* d_out, int out_size, void* d_ws, size_t ws_size,
                              hipStream_t stream) {
    const float* x  = (const float*)d_in[0];
    const float* wq = (const float*)d_in[1];
    const float* wk = (const float*)d_in[2];
    const float* wv = (const float*)d_in[3];
    const float* wo = (const float*)d_in[4];
    float* out = (float*)d_out;
    char* ws = (char*)d_ws;

    __bf16* Xb    = (__bf16*)ws;                        // [0, 8M)
    __bf16* WqkvT = (__bf16*)(ws + ((size_t)8 << 20));  // [8M, 20M)  3072 x 2048
    __bf16* WoT   = (__bf16*)(ws + ((size_t)20 << 20)); // [20M, 28M) 2048 x 2048
    __bf16* Qr    = (__bf16*)(ws + ((size_t)28 << 20)); // [28M, 36M) 32 x 2048 x 64
    __bf16* Kr    = (__bf16*)(ws + ((size_t)36 << 20)); // [36M, 38M)  8 x 2048 x 64
    __bf16* Vt    = (__bf16*)(ws + ((size_t)38 << 20)); // [38M, 40M)  8 x 64 x 2048
    __bf16* Ob    = (__bf16*)(ws + ((size_t)40 << 20)); // [40M, 48M) 2048 x 2048

    prep<<<4096 + 2560, 256, 0, stream>>>((const float4*)x, Xb, wq, wk, wv, wo, WqkvT, WoT);
    gemm_qkv<<<384, 256, 0, stream>>>(Xb, WqkvT, Qr, Kr, Vt);
    flash_attn<<<512, 512, 0, stream>>>(Qr, Kr, Vt, Ob);
    gemm_out<<<256, 256, 0, stream>>>(Ob, WoT, out);
}

// Round 12
// 197.138 us; speedup vs baseline: 1.1297x; 1.0047x over previous
//
#include <hip/hip_runtime.h>
#include <hip/hip_bf16.h>

typedef __bf16 bf16x8 __attribute__((ext_vector_type(8)));
typedef __bf16 bf16x4 __attribute__((ext_vector_type(4)));
typedef __bf16 bf16x2 __attribute__((ext_vector_type(2)));
typedef float fx4 __attribute__((ext_vector_type(4)));
typedef float fx16 __attribute__((ext_vector_type(16)));

#define AS1 __attribute__((address_space(1)))
#define AS3 __attribute__((address_space(3)))

// ---------------------------------------------------------------- prep: cast x -> bf16  +  all 4 weight transposes
__global__ __launch_bounds__(256) void prep(const float4* __restrict__ X, __bf16* __restrict__ Xb,
                                            const float* __restrict__ wq, const float* __restrict__ wk,
                                            const float* __restrict__ wv, const float* __restrict__ wo,
                                            __bf16* __restrict__ WqkvT, __bf16* __restrict__ WoT) {
    const int bx = blockIdx.x;
    if (bx < 4096) {
        const int i = bx * 256 + threadIdx.x;
        const float4 v = X[i];
        bf16x4 o = { (__bf16)v.x, (__bf16)v.y, (__bf16)v.z, (__bf16)v.w };
        *(bf16x4*)(Xb + (size_t)i * 4) = o;
        return;
    }
    constexpr int K = 2048;
    __shared__ float t[64][65];
    const int tt = bx - 4096;
    const float* W; __bf16* Wt; int N, loc;
    if (tt < 1024)      { W = wq; Wt = WqkvT;                       N = 2048; loc = tt; }
    else if (tt < 1280) { W = wk; Wt = WqkvT + (size_t)2048 * 2048; N = 512;  loc = tt - 1024; }
    else if (tt < 1536) { W = wv; Wt = WqkvT + (size_t)2560 * 2048; N = 512;  loc = tt - 1280; }
    else                { W = wo; Wt = WoT;                         N = 2048; loc = tt - 1536; }
    const int k0 = (loc & 31) * 64, n0 = (loc >> 5) * 64;
    const int tx = threadIdx.x & 15, ty = threadIdx.x >> 4;
#pragma unroll
    for (int p = 0; p < 4; ++p) {
        const float4 v = *(const float4*)&W[(size_t)(k0 + p * 16 + ty) * N + n0 + tx * 4];
        t[p * 16 + ty][tx * 4 + 0] = v.x;
        t[p * 16 + ty][tx * 4 + 1] = v.y;
        t[p * 16 + ty][tx * 4 + 2] = v.z;
        t[p * 16 + ty][tx * 4 + 3] = v.w;
    }
    __syncthreads();
#pragma unroll
    for (int p = 0; p < 4; ++p) {
        const int nn = p * 16 + ty;
        bf16x4 o = { (__bf16)t[tx * 4 + 0][nn], (__bf16)t[tx * 4 + 1][nn],
                     (__bf16)t[tx * 4 + 2][nn], (__bf16)t[tx * 4 + 3][nn] };
        *(bf16x4*)&Wt[(size_t)(n0 + nn) * K + k0 + tx * 4] = o;
    }
}

// ================================================= shared GEMM body: BM=128 BN=128 BK=32,
// 4 waves (64x64 wave-tile), 3-buffer depth-2 counted-vmcnt ring (48KB -> 3 blocks/CU),
// static buffer indices, XOR-swizzled LDS. 16 MFMA : 8 ds_read_b128 per K-step.
#define GL(p, d) __builtin_amdgcn_global_load_lds((const AS1 void*)(p), (AS3 void*)(d), 16, 0, 0)
#define WBAR(N)  asm volatile("s_waitcnt vmcnt(" #N ") lgkmcnt(0)" ::: "memory");             \
                 __builtin_amdgcn_s_barrier();                                                \
                 __builtin_amdgcn_sched_barrier(0)

#define GEMM_SETUP(Aptr, Btptr)                                                              \
    constexpr int K = 2048;                                                                  \
    __shared__ __align__(16) __bf16 sm[3][8192];    /* 48 KB */                              \
    const int tid = threadIdx.x;                                                             \
    const int wave = tid >> 6, lane = tid & 63;                                              \
    const int quad = lane >> 4, l16 = lane & 15;                                             \
    const int wm = (wave >> 1) * 64, wn = (wave & 1) * 64;                                   \
    fx4 acc[4][4] = {};                                                                      \
    const int r4 = lane >> 2;                                                                \
    const int c8s = ((lane & 3) ^ ((r4 >> 1) & 3)) * 8;                                      \
    const __bf16* csrc[4]; int cdst[4];                                                      \
    _Pragma("unroll")                                                                        \
    for (int it = 0; it < 4; ++it) {                                                         \
        const int idx = wave * 4 + it;                                                       \
        if (idx < 8) { csrc[it] = (Aptr) + (size_t)(m0 + idx * 16 + r4) * K + c8s;           \
                       cdst[it] = idx * 512 + lane * 8; }                                    \
        else         { csrc[it] = (Btptr) + (size_t)(n0 + (idx - 8) * 16 + r4) * K + c8s;    \
                       cdst[it] = 4096 + (idx - 8) * 512 + lane * 8; }                       \
    }                                                                                        \
    const int colr = (quad ^ ((l16 >> 1) & 3)) * 8;                                          \
    const int arow = (wm + l16) * 32 + colr;                                                 \
    const int brow = 4096 + (wn + l16) * 32 + colr;                                          \
    auto compute = [&](const __bf16* cb) {                                                   \
        bf16x8 af[4], bfr[4];                                                                \
        _Pragma("unroll") for (int i = 0; i < 4; ++i) af[i]  = *(const bf16x8*)&cb[arow + i * 512]; \
        _Pragma("unroll") for (int j = 0; j < 4; ++j) bfr[j] = *(const bf16x8*)&cb[brow + j * 512]; \
        __builtin_amdgcn_s_setprio(1);                                                       \
        _Pragma("unroll") for (int i = 0; i < 4; ++i)                                        \
            _Pragma("unroll") for (int j = 0; j < 4; ++j)                                    \
                acc[i][j] = __builtin_amdgcn_mfma_f32_16x16x32_bf16(af[i], bfr[j], acc[i][j], 0, 0, 0); \
        __builtin_amdgcn_s_setprio(0);                                                       \
    };                                                                                       \
    _Pragma("unroll")                                                                        \
    for (int pt = 0; pt < 2; ++pt)                                                           \
        _Pragma("unroll")                                                                    \
        for (int it = 0; it < 4; ++it)                                                       \
            GL(csrc[it] + pt * 32, &sm[pt][cdst[it]]);                                       \
    _Pragma("unroll 1")                                                                      \
    for (int tq = 0; tq < 20; ++tq) {                                                        \
        _Pragma("unroll")                                                                    \
        for (int u = 0; u < 3; ++u) {                                                        \
            const int t = tq * 3 + u;                                                        \
            WBAR(4);                                                                         \
            const int kofs = (t + 2) * 32;                                                   \
            _Pragma("unroll")                                                                \
            for (int it = 0; it < 4; ++it)                                                   \
                GL(csrc[it] + kofs, &sm[(u + 2) % 3][cdst[it]]);                             \
            compute(sm[u]);                                                                  \
        }                                                                                    \
    }                                                                                        \
    { WBAR(4); _Pragma("unroll") for (int it = 0; it < 4; ++it)                              \
          GL(csrc[it] + 62 * 32, &sm[2][cdst[it]]); compute(sm[0]); }  /* t=60 */            \
    { WBAR(4); _Pragma("unroll") for (int it = 0; it < 4; ++it)                              \
          GL(csrc[it] + 63 * 32, &sm[0][cdst[it]]); compute(sm[1]); }  /* t=61 */            \
    { WBAR(4); compute(sm[2]); }                                       /* t=62 */            \
    { WBAR(0); compute(sm[0]); }                                       /* t=63 */

// ------------------------------------------------- QKV GEMM with fused RoPE/split epilogue
__global__ __launch_bounds__(256, 3) void gemm_qkv(const __bf16* __restrict__ A, const __bf16* __restrict__ Bt,
                                                   __bf16* __restrict__ Qr, __bf16* __restrict__ Kr,
                                                   __bf16* __restrict__ Vt) {
    // XCD-chunked swizzle, nwg = 384 = 8*48
    const int bid = blockIdx.x;
    const int swz = (bid & 7) * 48 + (bid >> 3);
    const int m0 = (swz & 15) * 128, n0 = (swz >> 4) * 128;

    GEMM_SETUP(A, Bt)

    // epilogue: each wave's 64 cols (col64..col64+63) are exactly one head
    const int col64 = n0 + wn;
    if (col64 < 2560) {
        const bool isQ = col64 < 2048;
        const float scale = isQ ? 0.18033688011112042f : 1.0f;   // Q: 0.125*log2(e)
        __bf16* base = isQ ? (Qr + (size_t)(col64 >> 6) * 2048 * 64)
                           : (Kr + (size_t)((col64 - 2048) >> 6) * 2048 * 64);
#pragma unroll
        for (int jj = 0; jj < 2; ++jj) {
            const int dlo = jj * 16 + l16;
            const float inv = __builtin_amdgcn_exp2f(-(float)dlo * 0.41524101186092029f);
#pragma unroll
            for (int i = 0; i < 4; ++i)
#pragma unroll
                for (int r = 0; r < 4; ++r) {
                    const int s = m0 + wm + i * 16 + quad * 4 + r;
                    float sn, cs;
                    __sincosf((float)s * inv, &sn, &cs);
                    const float lo = acc[i][jj][r], hv = acc[i][jj + 2][r];
                    base[(size_t)s * 64 + dlo]      = (__bf16)((lo * cs - hv * sn) * scale);
                    base[(size_t)s * 64 + dlo + 32] = (__bf16)((hv * cs + lo * sn) * scale);
                }
        }
    } else {
        __bf16* vb = Vt + (size_t)((col64 - 2560) >> 6) * 64 * 2048;
#pragma unroll
        for (int i = 0; i < 4; ++i)
#pragma unroll
            for (int j = 0; j < 4; ++j) {
                const int d = j * 16 + l16;
                const int s0 = m0 + wm + i * 16 + quad * 4;
                bf16x4 p;
#pragma unroll
                for (int r = 0; r < 4; ++r) p[r] = (__bf16)acc[i][j][r];
                *(bf16x4*)&vb[(size_t)d * 2048 + s0] = p;
            }
    }
}

// ------------------------------------------------- out-projection GEMM, f32 C direct
__global__ __launch_bounds__(256, 3) void gemm_out(const __bf16* __restrict__ A, const __bf16* __restrict__ Bt,
                                                   float* __restrict__ C) {
    // XCD-chunked swizzle, nwg = 256 = 8*32
    const int bid = blockIdx.x;
    const int swz = (bid & 7) * 32 + (bid >> 3);
    const int m0 = (swz & 15) * 128, n0 = (swz >> 4) * 128;

    GEMM_SETUP(A, Bt)

#pragma unroll
    for (int i = 0; i < 4; ++i)
#pragma unroll
        for (int j = 0; j < 4; ++j) {
            const int row = m0 + wm + i * 16 + quad * 4;
            const int col = n0 + wn + j * 16 + l16;
#pragma unroll
            for (int r = 0; r < 4; ++r)
                C[(size_t)(row + r) * 2048 + col] = acc[i][j][r];
        }
}

// ------------------------------------------------- flash attention: 256-thr / 4-wave blocks,
// NO split-K: each wave owns 32 q-rows and iterates ALL 2048 keys (32 iters x 64-key tiles).
// Same per-iteration code, 72-stride conflict-free K/V layouts, and register set as the
// proven r6 kernel — only the block granularity changes: LDS 36864 B -> 4 independent
// blocks/CU at random phases (phase-mixing across blocks), barrier syncs exactly the 4 waves
// sharing the staged tile. Cross-group combine epilogue deleted (each wave owns its rows).
__global__ __launch_bounds__(256, 4) void flash_attn(const __bf16* __restrict__ Qr, const __bf16* __restrict__ Kr,
                                                     const __bf16* __restrict__ Vt, __bf16* __restrict__ O) {
    constexpr int S = 2048;
    __shared__ __align__(16) __bf16 smem[2][2 * 4608];   // [buf][K 64x72 | V 64x72-slot] = 36864 B
    const int qt = blockIdx.x, h = blockIdx.y, kvh = h >> 2;
    const int tid = threadIdx.x, wave = tid >> 6, lane = tid & 63;
    const int l32 = lane & 31, hi = lane >> 5;

    const int qrow = qt * 128 + wave * 32 + l32;
    const __bf16* qptr = Qr + ((size_t)h * S + qrow) * 64;
    bf16x8 qf[4];
#pragma unroll
    for (int kc = 0; kc < 4; ++kc) qf[kc] = *(const bf16x8*)(qptr + kc * 16 + hi * 8);

    const __bf16* Kbase = Kr + (size_t)kvh * S * 64;
    const __bf16* Vbase = Vt + (size_t)kvh * 64 * S;

    // staging: 256 threads cover the 64x64 K tile and V tile
    const int krow = tid >> 3;                  // 0..31
    const int kcol = (tid & 7) * 8;
    const int vslot = (kcol & 48) | ((kcol & 8) >> 1);   // permuted dest of keys [kcol, kcol+4)

    bf16x8 kreg0, kreg1, vreg0, vreg1;

#define LOADREGS(KT) do {                                                             \
        const size_t co = (size_t)(KT) * 64;                                          \
        kreg0 = *(const bf16x8*)(Kbase + (co + krow) * 64 + kcol);                    \
        kreg1 = *(const bf16x8*)(Kbase + (co + 32 + krow) * 64 + kcol);               \
        vreg0 = *(const bf16x8*)(Vbase + (size_t)krow * S + co + kcol);               \
        vreg1 = *(const bf16x8*)(Vbase + (size_t)(32 + krow) * S + co + kcol);        \
    } while (0)

#define STAGEB(BUF) do {                                                              \
        __bf16* nK = &smem[BUF][0];                                                   \
        __bf16* nV = nK + 4608;                                                       \
        *(bf16x8*)&nK[krow * 72 + kcol] = kreg0;                                      \
        *(bf16x8*)&nK[(32 + krow) * 72 + kcol] = kreg1;                               \
        bf16x4 v0lo = { vreg0[0], vreg0[1], vreg0[2], vreg0[3] };                     \
        bf16x4 v0hi = { vreg0[4], vreg0[5], vreg0[6], vreg0[7] };                     \
        bf16x4 v1lo = { vreg1[0], vreg1[1], vreg1[2], vreg1[3] };                     \
        bf16x4 v1hi = { vreg1[4], vreg1[5], vreg1[6], vreg1[7] };                     \
        *(bf16x4*)&nV[krow * 72 + vslot]            = v0lo;                           \
        *(bf16x4*)&nV[krow * 72 + vslot + 8]        = v0hi;                           \
        *(bf16x4*)&nV[(32 + krow) * 72 + vslot]     = v1lo;                           \
        *(bf16x4*)&nV[(32 + krow) * 72 + vslot + 8] = v1hi;                           \
    } while (0)

    fx16 ov0, ov1;
#pragma unroll
    for (int i = 0; i < 16; ++i) { ov0[i] = 0.f; ov1[i] = 0.f; }
    float l_acc = 0.f;

    // prologue: regs for tile 0, stage into buf 0, prefetch tile 1
    LOADREGS(0);
    STAGEB(0);
    LOADREGS(1);
    asm volatile("s_waitcnt lgkmcnt(0)" ::: "memory");
    __builtin_amdgcn_s_barrier();
    __builtin_amdgcn_sched_barrier(0);

    for (int it = 0; it < 32; ++it) {
        const __bf16* lKg = &smem[it & 1][0];
        const __bf16* lVg = lKg + 4608;

        // stage tile it+1 into the other buffer; prefetch tile it+2
        if (it + 1 < 32) {
            STAGEB((it + 1) & 1);
            LOADREGS((it + 2 < 32) ? it + 2 : 31);   // clamped (redundant reload ok)
        }

        // S^T = K . Q^T  (k-chunks of 16 d)
        fx16 sc0, sc1;
#pragma unroll
        for (int i = 0; i < 16; ++i) { sc0[i] = 0.f; sc1[i] = 0.f; }
        __builtin_amdgcn_s_setprio(1);
#pragma unroll
        for (int kc = 0; kc < 4; ++kc) {
            const bf16x8 a0 = *(const bf16x8*)&lKg[l32 * 72 + kc * 16 + hi * 8];
            const bf16x8 a1 = *(const bf16x8*)&lKg[(32 + l32) * 72 + kc * 16 + hi * 8];
            sc0 = __builtin_amdgcn_mfma_f32_32x32x16_bf16(a0, qf[kc], sc0, 0, 0, 0);
            sc1 = __builtin_amdgcn_mfma_f32_32x32x16_bf16(a1, qf[kc], sc1, 0, 0, 0);
        }
        __builtin_amdgcn_s_setprio(0);

        // fixed-max softmax (p = exp2(s), Q pre-scaled) fused straight into PV;
        // l summed per-octet tree (depth 4)
#pragma unroll
        for (int h2 = 0; h2 < 2; ++h2) {
#pragma unroll
            for (int c = 0; c < 2; ++c) {
                bf16x8 pb; float ps[8];
#pragma unroll
                for (int j = 0; j < 8; ++j) {
                    const float sv = h2 ? sc1[c * 8 + j] : sc0[c * 8 + j];
                    ps[j] = __builtin_amdgcn_exp2f(sv);
                    pb[j] = (__bf16)ps[j];
                }
                l_acc += ((ps[0] + ps[1]) + (ps[2] + ps[3]))
                       + ((ps[4] + ps[5]) + (ps[6] + ps[7]));
                const int kcv = h2 * 2 + c;
                const bf16x8 va0 = *(const bf16x8*)&lVg[l32 * 72 + kcv * 16 + hi * 8];
                const bf16x8 va1 = *(const bf16x8*)&lVg[(32 + l32) * 72 + kcv * 16 + hi * 8];
                __builtin_amdgcn_s_setprio(1);
                ov0 = __builtin_amdgcn_mfma_f32_32x32x16_bf16(va0, pb, ov0, 0, 0, 0);
                ov1 = __builtin_amdgcn_mfma_f32_32x32x16_bf16(va1, pb, ov1, 0, 0, 0);
                __builtin_amdgcn_s_setprio(0);
            }
        }
        asm volatile("s_waitcnt lgkmcnt(0)" ::: "memory");
        __builtin_amdgcn_s_barrier();
        __builtin_amdgcn_sched_barrier(0);
    }

    // per-q-row l: lane^32 holds the complementary 32 key-slots of each tile
    const float l_pair = l_acc + __shfl_xor(l_acc, 32, 64);
    const float inv_l = 1.0f / l_pair;

    // direct write — every wave owns its 32 q-rows fully (no cross-group combine)
#pragma unroll
    for (int dt = 0; dt < 2; ++dt)
#pragma unroll
        for (int rg2 = 0; rg2 < 4; ++rg2) {
            bf16x4 o4;
#pragma unroll
            for (int r = 0; r < 4; ++r)
                o4[r] = (__bf16)((dt ? ov1[rg2 * 4 + r] : ov0[rg2 * 4 + r]) * inv_l);
            const int col = h * 64 + dt * 32 + rg2 * 8 + hi * 4;
            *(bf16x4*)(O + (size_t)qrow * 2048 + col) = o4;
        }
#undef LOADREGS
#undef STAGEB
}

// ----------------------------------------------------------------------------
extern "C" void kernel_launch(void* const* d_in, const int* in_sizes, int n_in,
                              void* d_out, int out_size, void* d_ws, size_t ws_size,
                              hipStream_t stream) {
    const float* x  = (const float*)d_in[0];
    const float* wq = (const float*)d_in[1];
    const float* wk = (const float*)d_in[2];
    const float* wv = (const float*)d_in[3];
    const float* wo = (const float*)d_in[4];
    float* out = (float*)d_out;
    char* ws = (char*)d_ws;

    __bf16* Xb    = (__bf16*)ws;                        // [0, 8M)
    __bf16* WqkvT = (__bf16*)(ws + ((size_t)8 << 20));  // [8M, 20M)  3072 x 2048
    __bf16* WoT   = (__bf16*)(ws + ((size_t)20 << 20)); // [20M, 28M) 2048 x 2048
    __bf16* Qr    = (__bf16*)(ws + ((size_t)28 << 20)); // [28M, 36M) 32 x 2048 x 64
    __bf16* Kr    = (__bf16*)(ws + ((size_t)36 << 20)); // [36M, 38M)  8 x 2048 x 64
    __bf16* Vt    = (__bf16*)(ws + ((size_t)38 << 20)); // [38M, 40M)  8 x 64 x 2048
    __bf16* Ob    = (__bf16*)(ws + ((size_t)40 << 20)); // [40M, 48M) 2048 x 2048

    prep<<<4096 + 2560, 256, 0, stream>>>((const float4*)x, Xb, wq, wk, wv, wo, WqkvT, WoT);
    gemm_qkv<<<384, 256, 0, stream>>>(Xb, WqkvT, Qr, Kr, Vt);
    flash_attn<<<dim3(16, 32), 256, 0, stream>>>(Qr, Kr, Vt, Ob);
    gemm_out<<<256, 256, 0, stream>>>(Ob, WoT, out);
}